// Round 2
// baseline (13435.371 us; speedup 1.0000x reference)
//
#include <hip/hip_runtime.h>
#include <stdint.h>

#define NB 512   // batch
#define NT 32    // time steps
#define NIN 8    // input feats
#define NIN1 9   // + y_prev
#define NH 64    // hidden
#define NP 256   // particles
#define NTHR 512 // 2 k-halves x 256 particles
#define KH (NH/2)

struct FKeys { uint32_t a[NT]; uint32_t b[NT]; };

// ---------------- Threefry-2x32-20 (exact JAX semantics) ----------------
__host__ __device__ __forceinline__ void tfr(uint32_t& x0, uint32_t& x1, int r) {
  x0 += x1; x1 = (x1 << r) | (x1 >> (32 - r)); x1 ^= x0;
}

__host__ __device__ __forceinline__ void threefry2x32(uint32_t k0, uint32_t k1,
                                                      uint32_t& x0, uint32_t& x1) {
  uint32_t k2 = k0 ^ k1 ^ 0x1BD11BDAu;
  x0 += k0; x1 += k1;
  tfr(x0,x1,13); tfr(x0,x1,15); tfr(x0,x1,26); tfr(x0,x1,6);
  x0 += k1; x1 += k2 + 1u;
  tfr(x0,x1,17); tfr(x0,x1,29); tfr(x0,x1,16); tfr(x0,x1,24);
  x0 += k2; x1 += k0 + 2u;
  tfr(x0,x1,13); tfr(x0,x1,15); tfr(x0,x1,26); tfr(x0,x1,6);
  x0 += k0; x1 += k1 + 3u;
  tfr(x0,x1,17); tfr(x0,x1,29); tfr(x0,x1,16); tfr(x0,x1,24);
  x0 += k1; x1 += k2 + 4u;
  tfr(x0,x1,13); tfr(x0,x1,15); tfr(x0,x1,26); tfr(x0,x1,6);
  x0 += k2; x1 += k0 + 5u;
}

// bits -> uniform(nextafter(-1,0), 1) -> sqrt(2)*erfinv  (XLA f32 path) — keep EXACT
__device__ __forceinline__ float normal_from_bits(uint32_t bits) {
  float f = __uint_as_float((bits >> 9) | 0x3f800000u) - 1.0f;  // [0,1)
  const float lo = -0.99999994f;                                 // nextafter(-1,0)
  float u = fmaxf(lo, fmaf(f, 2.0f, lo));                        // (hi-lo) rounds to 2.0f
  float w = -log1pf(-u * u);
  float p;
  if (w < 5.0f) {
    w -= 2.5f;
    p = 2.81022636e-08f;
    p = fmaf(p, w, 3.43273939e-07f);
    p = fmaf(p, w, -3.5233877e-06f);
    p = fmaf(p, w, -4.39150654e-06f);
    p = fmaf(p, w, 0.00021858087f);
    p = fmaf(p, w, -0.00125372503f);
    p = fmaf(p, w, -0.00417768164f);
    p = fmaf(p, w, 0.246640727f);
    p = fmaf(p, w, 1.50140941f);
  } else {
    w = sqrtf(w) - 3.0f;
    p = -0.000200214257f;
    p = fmaf(p, w, 0.000100950558f);
    p = fmaf(p, w, 0.00134934322f);
    p = fmaf(p, w, -0.00367342844f);
    p = fmaf(p, w, 0.00573950773f);
    p = fmaf(p, w, -0.0076224613f);
    p = fmaf(p, w, 0.00943887047f);
    p = fmaf(p, w, 1.00167406f);
    p = fmaf(p, w, 2.83297682f);
  }
  return 1.41421356f * (p * u);
}

__device__ __forceinline__ float frcp(float x) { return __builtin_amdgcn_rcpf(x); }
__device__ __forceinline__ float fsigmoid(float x) { return frcp(1.0f + __expf(-x)); }
__device__ __forceinline__ float ftanh(float x) { return 1.0f - 2.0f * frcp(1.0f + __expf(2.0f * x)); }

// ---------------- main kernel: one block (512 thr) per batch elem ----------------
// waves 0-3: half 0 (k in [0,32)), waves 4-7: half 1 (k in [32,64)); p = tid & 255
__global__ __launch_bounds__(NTHR, 4)
void pf_main(const float* __restrict__ input_data, const float* __restrict__ y_prev,
             const float* __restrict__ Wv, const float* __restrict__ bv,
             const float* __restrict__ W_ih, const float* __restrict__ W_hh,
             const float* __restrict__ b_ih, const float* __restrict__ b_hh,
             const float* __restrict__ Wp, const float* __restrict__ bp,
             const float* __restrict__ Wf, const float* __restrict__ bf,
             float* __restrict__ out, float* __restrict__ cbuf, float* __restrict__ gw,
             FKeys fk)
{
  __shared__ float hBuf[NH * NP];                    // 64 KB, [k][p]
  __shared__ __align__(16) float xg4_s[NH * 4];      // [k][gate i,f,g,o]
  __shared__ float projP[2][NP];
  __shared__ float lpP[2][NP];
  __shared__ __align__(16) float projC[NP];
  __shared__ float wsum_s[NP];
  __shared__ float red_s[4][NH];
  __shared__ float hmean_s[NH];
  __shared__ float std_s[NH];
  __shared__ float xs_s[16];

  const int tid   = threadIdx.x;
  const int b     = blockIdx.x;
  const int p     = tid & (NP - 1);
  const int half  = tid >> 8;            // wave-aligned: waves 0-3 -> 0, 4-7 -> 1
  const int kbase = half * KH;
  const int lane  = tid & 63;
  const int wid   = tid >> 6;

  // init: each half zeroes its own k-rows (all columns)
  #pragma unroll
  for (int i = 0; i < KH; ++i) hBuf[(kbase + i) * NP + p] = 0.0f;
  if (tid < NP) wsum_s[tid] = 0.0f;

  // per-thread constants
  float wih_r[NIN1];
  float bihh = 0.0f;
  if (tid < 4 * NH) {
    #pragma unroll
    for (int i = 0; i < NIN1; ++i) wih_r[i] = W_ih[tid * NIN1 + i];
    bihh = b_ih[tid] + b_hh[tid];
  }
  const float bv_r = (tid < NH) ? bv[tid] : 0.0f;
  const float bf0  = bf[0];
  const float bp0  = bp[0];
  const uint32_t xbase = ((uint32_t)(p & 127) << 15) | ((uint32_t)b << 6);
  const bool hihalf = (p >= 128);

  __syncthreads();

  for (int t = 0; t < NT; ++t) {
    // ---- A: x_t load, own h column -> regs, cross-particle partial sums ----
    if (tid < NIN) xs_s[tid] = input_data[(b * NT + t) * NIN + tid];
    if (tid == NIN) xs_s[NIN] = y_prev[b * NT + t];

    float h_reg[NH];
    #pragma unroll
    for (int j = 0; j < NH; ++j) h_reg[j] = hBuf[j * NP + p];

    if (half == 0) {
      #pragma unroll
      for (int j = 0; j < NH; ++j) {
        float s = h_reg[j];
        s += __shfl_xor(s, 32, 64);
        s += __shfl_xor(s, 16, 64);
        s += __shfl_xor(s, 8, 64);
        s += __shfl_xor(s, 4, 64);
        s += __shfl_xor(s, 2, 64);
        s += __shfl_xor(s, 1, 64);
        if (lane == 0) red_s[wid][j] = s;
      }
    }
    __syncthreads();

    // ---- B: hidden_mean + x-part of all 256 gates ----
    if (tid < NH)
      hmean_s[tid] = (red_s[0][tid] + red_s[1][tid] + red_s[2][tid] + red_s[3][tid]) * (1.0f / NP);
    if (tid < 4 * NH) {
      float a = bihh;
      #pragma unroll
      for (int i = 0; i < NIN1; ++i) a = fmaf(xs_s[i], wih_r[i], a);
      xg4_s[(tid & 63) * 4 + (tid >> 6)] = a;   // [k][gate]
    }
    __syncthreads();

    // ---- C: std = softplus(concat(x, hmean) @ Wv.T + bv)  (keep libm, exact) ----
    if (tid < NH) {
      float v = bv_r;
      const float* wvr = Wv + tid * (NIN1 + NH);
      #pragma unroll
      for (int i = 0; i < NIN1; ++i) v = fmaf(xs_s[i], wvr[i], v);
      #pragma unroll
      for (int k = 0; k < NH; ++k) v = fmaf(hmean_s[k], wvr[NIN1 + k], v);
      std_s[tid] = fmaxf(v, 0.0f) + log1pf(expf(-fabsf(v)));
    }
    __syncthreads();

    // ---- D: LSTM cell for own 32 k's; proj/logpdf partials on the fly ----
    const uint32_t fk0 = fk.a[t], fk1 = fk.b[t];
    const bool t0 = (t == 0);
    float proj_acc = (half == 0) ? bf0 : 0.0f;
    float lp_acc = 0.0f;
    const size_t cbase = ((size_t)b * NH + kbase) * NP + p;
    float craw = cbuf[cbase];                 // poison at t==0 is discarded below
    float cold = t0 ? 0.0f : craw;
    #pragma unroll 2
    for (int i = 0; i < KH; ++i) {
      const int k = kbase + i;
      float cnraw = 0.0f;
      if (i + 1 < KH) cnraw = cbuf[cbase + (size_t)(i + 1) * NP];   // prefetch next c
      const float4 xg = *(const float4*)&xg4_s[k * 4];
      const float* wi  = W_hh + (0 * NH + k) * NH;
      const float* wf_ = W_hh + (1 * NH + k) * NH;
      const float* wg  = W_hh + (2 * NH + k) * NH;
      const float* wo  = W_hh + (3 * NH + k) * NH;
      float ai = xg.x, af = xg.y, ag = xg.z, ao = xg.w;
      #pragma unroll
      for (int j = 0; j < NH; ++j) {
        ai = fmaf(h_reg[j], wi[j],  ai);
        af = fmaf(h_reg[j], wf_[j], af);
        ag = fmaf(h_reg[j], wg[j],  ag);
        ao = fmaf(h_reg[j], wo[j],  ao);
      }
      float si = fsigmoid(ai);
      float sf = fsigmoid(af);
      float so = fsigmoid(ao);
      float cn = sf * cold + si * ftanh(ag);
      cbuf[cbase + (size_t)i * NP] = cn;       // c is NOT sorted
      float hl = so * ftanh(cn);
      uint32_t x0 = xbase | (uint32_t)k;       // pair (m, m+2^22)
      uint32_t x1 = x0 + (1u << 22);
      threefry2x32(fk0, fk1, x0, x1);
      float eps = normal_from_bits(hihalf ? x1 : x0);
      float hrep = fmaf(eps, std_s[k], hl);
      hBuf[k * NP + p] = hrep;                 // own cell, pre-sort
      proj_acc = fmaf(hrep, Wf[k], proj_acc);
      lp_acc   = fmaf(hrep, Wp[k], lp_acc);
      cold = t0 ? 0.0f : cnraw;
    }

    projP[half][p] = proj_acc;
    lpP[half][p]   = lp_acc;
    __syncthreads();

    const float projv = projP[0][p] + projP[1][p];
    if (half == 0) projC[p] = projv;
    __syncthreads();

    // ---- stable rank (ascending, ties by index) == argsort slot ----
    int rank = 0;
    const float4* p4 = (const float4*)projC;
    #pragma unroll 8
    for (int q4 = 0; q4 < NP / 4; ++q4) {
      float4 v = p4[q4];
      int qb = q4 * 4;
      rank += (v.x < projv || (v.x == projv && qb + 0 < p)) ? 1 : 0;
      rank += (v.y < projv || (v.y == projv && qb + 1 < p)) ? 1 : 0;
      rank += (v.z < projv || (v.z == projv && qb + 2 < p)) ? 1 : 0;
      rank += (v.w < projv || (v.w == projv && qb + 3 < p)) ? 1 : 0;
    }

    // ---- logpdf at sorted slot; accumulate exp into wsum by slot (half0 only) ----
    if (half == 0) {
      float lpv = lpP[0][p] + lpP[1][p];
      float xpart = bp0;
      #pragma unroll
      for (int i = 0; i < NIN1; ++i) xpart = fmaf(xs_s[i], Wp[NH + i], xpart);
      wsum_s[rank] += __expf(lpv + xpart);     // ranks are a permutation -> race-free
    }

    // ---- sort scatter: read own rows to regs, barrier, write at rank ----
    float h_ex[KH];
    #pragma unroll
    for (int i = 0; i < KH; ++i) h_ex[i] = hBuf[(kbase + i) * NP + p];
    __syncthreads();
    #pragma unroll
    for (int i = 0; i < KH; ++i) hBuf[(kbase + i) * NP + rank] = h_ex[i];
    __syncthreads();
  }

  // ---- epilogue: y_pred[b] = mean_p(h_fin) @ Wf + bf ----
  if (half == 0) {
    #pragma unroll
    for (int j = 0; j < NH; ++j) {
      float s = hBuf[j * NP + p];
      s += __shfl_xor(s, 32, 64);
      s += __shfl_xor(s, 16, 64);
      s += __shfl_xor(s, 8, 64);
      s += __shfl_xor(s, 4, 64);
      s += __shfl_xor(s, 2, 64);
      s += __shfl_xor(s, 1, 64);
      if (lane == 0) red_s[wid][j] = s;
    }
  }
  __syncthreads();
  if (tid < NH) {
    float hm = (red_s[0][tid] + red_s[1][tid] + red_s[2][tid] + red_s[3][tid]) * (1.0f / NP);
    float contrib = hm * Wf[tid];
    contrib += __shfl_xor(contrib, 32, 64);
    contrib += __shfl_xor(contrib, 16, 64);
    contrib += __shfl_xor(contrib, 8, 64);
    contrib += __shfl_xor(contrib, 4, 64);
    contrib += __shfl_xor(contrib, 2, 64);
    contrib += __shfl_xor(contrib, 1, 64);
    if (tid == 0) out[b] = contrib + bf0;
  }
  if (tid < NP) gw[(size_t)tid * NB + b] = wsum_s[tid];
}

// weights[i] = (1/256) * sum_{j<256} gw[(i>>1)*512 + (i&1)*256 + j]
__global__ __launch_bounds__(64, 1)
void pf_weights(const float* __restrict__ gw, float* __restrict__ out) {
  int i = blockIdx.x;
  int lane = threadIdx.x;
  const float* src = gw + ((size_t)(i >> 1)) * NB + (size_t)(i & 1) * NP;
  float4 v = ((const float4*)src)[lane];
  float s = (v.x + v.y) + (v.z + v.w);
  s += __shfl_xor(s, 32, 64);
  s += __shfl_xor(s, 16, 64);
  s += __shfl_xor(s, 8, 64);
  s += __shfl_xor(s, 4, 64);
  s += __shfl_xor(s, 2, 64);
  s += __shfl_xor(s, 1, 64);
  if (lane == 0) out[NB + i] = s * (1.0f / NP);
}

extern "C" void kernel_launch(void* const* d_in, const int* in_sizes, int n_in,
                              void* d_out, int out_size, void* d_ws, size_t ws_size,
                              hipStream_t stream) {
  (void)in_sizes; (void)n_in; (void)out_size; (void)ws_size;
  const float* input_data = (const float*)d_in[0];
  const float* y_prev     = (const float*)d_in[1];
  const float* Wv         = (const float*)d_in[2];
  const float* bv         = (const float*)d_in[3];
  const float* W_ih       = (const float*)d_in[4];
  const float* W_hh       = (const float*)d_in[5];
  const float* b_ih       = (const float*)d_in[6];
  const float* b_hh       = (const float*)d_in[7];
  const float* Wp         = (const float*)d_in[8];
  const float* bp         = (const float*)d_in[9];
  const float* Wf         = (const float*)d_in[10];
  const float* bf         = (const float*)d_in[11];
  float* out  = (float*)d_out;
  float* cbuf = (float*)d_ws;                          // [B][H][P] f32 = 33.5 MB
  float* gw   = cbuf + (size_t)NB * NH * NP;           // [P][B] f32 = 512 KB

  FKeys fk;
  for (int t = 0; t < NT; ++t) {
    uint32_t x0 = 0u, x1 = (uint32_t)t;
    threefry2x32(0u, 1234u, x0, x1);
    fk.a[t] = x0; fk.b[t] = x1;
  }

  pf_main<<<dim3(NB), dim3(NTHR), 0, stream>>>(
      input_data, y_prev, Wv, bv, W_ih, W_hh, b_ih, b_hh, Wp, bp, Wf, bf,
      out, cbuf, gw, fk);
  pf_weights<<<dim3(NB), dim3(64), 0, stream>>>(gw, out);
}

// Round 4
// 8527.026 us; speedup vs baseline: 1.5756x; 1.5756x over previous
//
#include <hip/hip_runtime.h>
#include <stdint.h>

#define NB 512   // batch
#define NT 32    // time steps
#define NIN 8    // input feats
#define NIN1 9   // + y_prev
#define NH 64    // hidden
#define NP 256   // particles
#define NTHR 512 // 2 k-halves x 256 particles
#define KH 32    // k's per thread-half
#define NHP 68   // padded h-row stride in floats (68*4=272B, 16B-aligned, bank-spread)

struct FKeys { uint32_t a[NT]; uint32_t b[NT]; };

// ---------------- Threefry-2x32-20 (exact JAX semantics) ----------------
__host__ __device__ __forceinline__ void tfr(uint32_t& x0, uint32_t& x1, int r) {
  x0 += x1; x1 = (x1 << r) | (x1 >> (32 - r)); x1 ^= x0;
}

__host__ __device__ __forceinline__ void threefry2x32(uint32_t k0, uint32_t k1,
                                                      uint32_t& x0, uint32_t& x1) {
  uint32_t k2 = k0 ^ k1 ^ 0x1BD11BDAu;
  x0 += k0; x1 += k1;
  tfr(x0,x1,13); tfr(x0,x1,15); tfr(x0,x1,26); tfr(x0,x1,6);
  x0 += k1; x1 += k2 + 1u;
  tfr(x0,x1,17); tfr(x0,x1,29); tfr(x0,x1,16); tfr(x0,x1,24);
  x0 += k2; x1 += k0 + 2u;
  tfr(x0,x1,13); tfr(x0,x1,15); tfr(x0,x1,26); tfr(x0,x1,6);
  x0 += k0; x1 += k1 + 3u;
  tfr(x0,x1,17); tfr(x0,x1,29); tfr(x0,x1,16); tfr(x0,x1,24);
  x0 += k1; x1 += k2 + 4u;
  tfr(x0,x1,13); tfr(x0,x1,15); tfr(x0,x1,26); tfr(x0,x1,6);
  x0 += k2; x1 += k0 + 5u;
}

// bits -> uniform(nextafter(-1,0), 1) -> sqrt(2)*erfinv  (XLA f32 path) — keep EXACT
__device__ __forceinline__ float normal_from_bits(uint32_t bits) {
  float f = __uint_as_float((bits >> 9) | 0x3f800000u) - 1.0f;  // [0,1)
  const float lo = -0.99999994f;                                 // nextafter(-1,0)
  float u = fmaxf(lo, fmaf(f, 2.0f, lo));                        // (hi-lo) rounds to 2.0f
  float w = -log1pf(-u * u);
  float p;
  if (w < 5.0f) {
    w -= 2.5f;
    p = 2.81022636e-08f;
    p = fmaf(p, w, 3.43273939e-07f);
    p = fmaf(p, w, -3.5233877e-06f);
    p = fmaf(p, w, -4.39150654e-06f);
    p = fmaf(p, w, 0.00021858087f);
    p = fmaf(p, w, -0.00125372503f);
    p = fmaf(p, w, -0.00417768164f);
    p = fmaf(p, w, 0.246640727f);
    p = fmaf(p, w, 1.50140941f);
  } else {
    w = sqrtf(w) - 3.0f;
    p = -0.000200214257f;
    p = fmaf(p, w, 0.000100950558f);
    p = fmaf(p, w, 0.00134934322f);
    p = fmaf(p, w, -0.00367342844f);
    p = fmaf(p, w, 0.00573950773f);
    p = fmaf(p, w, -0.0076224613f);
    p = fmaf(p, w, 0.00943887047f);
    p = fmaf(p, w, 1.00167406f);
    p = fmaf(p, w, 2.83297682f);
  }
  return 1.41421356f * (p * u);
}

__device__ __forceinline__ float frcp(float x) { return __builtin_amdgcn_rcpf(x); }
__device__ __forceinline__ float fsigmoid(float x) { return frcp(1.0f + __expf(-x)); }
__device__ __forceinline__ float ftanh(float x) { return 1.0f - 2.0f * frcp(1.0f + __expf(2.0f * x)); }

// ---------------- main kernel: one block (512 thr) per batch elem ----------------
// p = tid & 255 (particle slot), half = tid >> 8 (k-range), wave-aligned.
// hBuf layout: [p][NHP] particle-major; h row re-read from LDS per k-tile (no big
// per-thread register array -> no spills).
__global__ __launch_bounds__(NTHR, 4)
void pf_main(const float* __restrict__ input_data, const float* __restrict__ y_prev,
             const float* __restrict__ Wv, const float* __restrict__ bv,
             const float* __restrict__ W_ih, const float* __restrict__ W_hh,
             const float* __restrict__ b_ih, const float* __restrict__ b_hh,
             const float* __restrict__ Wp, const float* __restrict__ bp,
             const float* __restrict__ Wf, const float* __restrict__ bf,
             float* __restrict__ out, float* __restrict__ cbuf, float* __restrict__ gw,
             FKeys fk)
{
  __shared__ __align__(16) float hBuf[NP * NHP];     // 69.6 KB
  __shared__ float red8_s[8][NH];                    // 2 KB
  __shared__ __align__(16) float xg4_s[NH * 4];      // [k][gate i,f,g,o] 1 KB
  __shared__ float projP[2][NP];
  __shared__ float lpP[2][NP];
  __shared__ __align__(16) float projC[NP];
  __shared__ float wsum_s[NP];
  __shared__ float hmean_s[NH];
  __shared__ float std_s[NH];
  __shared__ float xs_s[16];

  const int tid   = threadIdx.x;
  const int b     = blockIdx.x;
  const int p     = tid & (NP - 1);
  const int half  = tid >> 8;
  const int kbase = half * KH;
  const int wid   = tid >> 6;        // 0..7
  const int j_a   = tid & 63;        // phase-A column

  for (int idx = tid; idx < NP * NHP; idx += NTHR) hBuf[idx] = 0.0f;
  if (tid < NP) wsum_s[tid] = 0.0f;

  float wih_r[NIN1];
  float bihh = 0.0f;
  if (tid < 4 * NH) {
    #pragma unroll
    for (int i = 0; i < NIN1; ++i) wih_r[i] = W_ih[tid * NIN1 + i];
    bihh = b_ih[tid] + b_hh[tid];
  }
  const float bv_r = (tid < NH) ? bv[tid] : 0.0f;
  const float bf0  = bf[0];
  const float bp0  = bp[0];
  const uint32_t xbase = ((uint32_t)(p & 127) << 15) | ((uint32_t)b << 6);
  const bool hih = (p >= 128);

  __syncthreads();

  for (int t = 0; t < NT; ++t) {
    if (tid < NIN) xs_s[tid] = input_data[(b * NT + t) * NIN + tid];
    if (tid == NIN) xs_s[NIN] = y_prev[b * NT + t];

    // ---- A: partial particle sums for hidden_mean (each thread sums 32 rows) ----
    {
      float s = 0.0f;
      const int p0 = wid * 32;
      #pragma unroll
      for (int pp = 0; pp < 32; ++pp) s += hBuf[(p0 + pp) * NHP + j_a];
      red8_s[wid][j_a] = s;
    }
    __syncthreads();

    // ---- B: hidden_mean + x-part of all 256 gates ----
    if (tid < NH) {
      float s = 0.0f;
      #pragma unroll
      for (int w = 0; w < 8; ++w) s += red8_s[w][tid];
      hmean_s[tid] = s * (1.0f / NP);
    }
    if (tid < 4 * NH) {
      float a = bihh;
      #pragma unroll
      for (int i = 0; i < NIN1; ++i) a = fmaf(xs_s[i], wih_r[i], a);
      xg4_s[(tid & 63) * 4 + (tid >> 6)] = a;   // [k][gate]
    }
    __syncthreads();

    // ---- C: std = softplus(concat(x, hmean) @ Wv.T + bv)  (libm, exact) ----
    if (tid < NH) {
      float v = bv_r;
      const float* wvr = Wv + tid * (NIN1 + NH);
      #pragma unroll
      for (int i = 0; i < NIN1; ++i) v = fmaf(xs_s[i], wvr[i], v);
      #pragma unroll
      for (int k = 0; k < NH; ++k) v = fmaf(hmean_s[k], wvr[NIN1 + k], v);
      std_s[tid] = fmaxf(v, 0.0f) + log1pf(expf(-fabsf(v)));
    }
    __syncthreads();

    // ---- D: LSTM cell, k-tiled (8 k per tile); h row re-read from LDS per tile ----
    const uint32_t fk0 = fk.a[t], fk1 = fk.b[t];
    const bool t0 = (t == 0);
    float proj_acc = half ? 0.0f : bf0;
    float lp_acc = 0.0f;
    const size_t cbase = ((size_t)b * NH + kbase) * NP + p;
    float hr0[8], hr1[8], hr2[8], hr3[8];   // new-h staging, static indices only

    #pragma unroll 1
    for (int kt = 0; kt < 4; ++kt) {
      const int kb = kbase + kt * 8;
      float cold[8];
      #pragma unroll
      for (int kk = 0; kk < 8; ++kk) cold[kk] = cbuf[cbase + (size_t)(kt * 8 + kk) * NP];

      float acc0[8], acc1[8], acc2[8], acc3[8];
      #pragma unroll
      for (int kk = 0; kk < 8; ++kk) {
        const float4 xg = *(const float4*)&xg4_s[(kb + kk) * 4];
        acc0[kk] = xg.x; acc1[kk] = xg.y; acc2[kk] = xg.z; acc3[kk] = xg.w;
      }

      #pragma unroll 1
      for (int j4 = 0; j4 < 16; ++j4) {
        const float4 h4 = *(const float4*)&hBuf[p * NHP + j4 * 4];
        const float* wj = W_hh + j4 * 4;
        #pragma unroll
        for (int kk = 0; kk < 8; ++kk) {
          const int kr = (kb + kk) * NH;
          const float* w0 = wj + kr;                 // gate i
          const float* w1 = wj + kr + NH * NH;       // gate f
          const float* w2 = wj + kr + 2 * NH * NH;   // gate g
          const float* w3 = wj + kr + 3 * NH * NH;   // gate o
          acc0[kk] = fmaf(h4.x, w0[0], acc0[kk]);
          acc0[kk] = fmaf(h4.y, w0[1], acc0[kk]);
          acc0[kk] = fmaf(h4.z, w0[2], acc0[kk]);
          acc0[kk] = fmaf(h4.w, w0[3], acc0[kk]);
          acc1[kk] = fmaf(h4.x, w1[0], acc1[kk]);
          acc1[kk] = fmaf(h4.y, w1[1], acc1[kk]);
          acc1[kk] = fmaf(h4.z, w1[2], acc1[kk]);
          acc1[kk] = fmaf(h4.w, w1[3], acc1[kk]);
          acc2[kk] = fmaf(h4.x, w2[0], acc2[kk]);
          acc2[kk] = fmaf(h4.y, w2[1], acc2[kk]);
          acc2[kk] = fmaf(h4.z, w2[2], acc2[kk]);
          acc2[kk] = fmaf(h4.w, w2[3], acc2[kk]);
          acc3[kk] = fmaf(h4.x, w3[0], acc3[kk]);
          acc3[kk] = fmaf(h4.y, w3[1], acc3[kk]);
          acc3[kk] = fmaf(h4.z, w3[2], acc3[kk]);
          acc3[kk] = fmaf(h4.w, w3[3], acc3[kk]);
        }
      }

      float tmp[8];
      #pragma unroll
      for (int kk = 0; kk < 8; ++kk) {
        const int k = kb + kk;
        float cprev = t0 ? 0.0f : cold[kk];
        float si = fsigmoid(acc0[kk]);
        float sf = fsigmoid(acc1[kk]);
        float so = fsigmoid(acc3[kk]);
        float cn = sf * cprev + si * ftanh(acc2[kk]);
        cbuf[cbase + (size_t)(kt * 8 + kk) * NP] = cn;   // c is NOT sorted
        float hl = so * ftanh(cn);
        uint32_t x0 = xbase | (uint32_t)k;               // pair (m, m+2^22)
        uint32_t x1 = x0 + (1u << 22);
        threefry2x32(fk0, fk1, x0, x1);
        float eps = normal_from_bits(hih ? x1 : x0);
        float hrep = fmaf(eps, std_s[k], hl);
        tmp[kk] = hrep;
        proj_acc = fmaf(hrep, Wf[k], proj_acc);
        lp_acc   = fmaf(hrep, Wp[k], lp_acc);
      }
      if (kt == 0) {
        #pragma unroll
        for (int kk = 0; kk < 8; ++kk) hr0[kk] = tmp[kk];
      } else if (kt == 1) {
        #pragma unroll
        for (int kk = 0; kk < 8; ++kk) hr1[kk] = tmp[kk];
      } else if (kt == 2) {
        #pragma unroll
        for (int kk = 0; kk < 8; ++kk) hr2[kk] = tmp[kk];
      } else {
        #pragma unroll
        for (int kk = 0; kk < 8; ++kk) hr3[kk] = tmp[kk];
      }
    }

    projP[half][p] = proj_acc;
    lpP[half][p]   = lp_acc;
    __syncthreads();                       // also: all hBuf reads of this t are done

    const float projv = projP[0][p] + projP[1][p];
    if (!half) projC[p] = projv;
    __syncthreads();

    // ---- stable rank (ascending, ties by current index) == argsort slot ----
    int rank = 0;
    const float4* c4 = (const float4*)projC;
    #pragma unroll 8
    for (int q4 = 0; q4 < NP / 4; ++q4) {
      float4 v = c4[q4];
      int qb = q4 * 4;
      rank += (v.x < projv || (v.x == projv && qb + 0 < p)) ? 1 : 0;
      rank += (v.y < projv || (v.y == projv && qb + 1 < p)) ? 1 : 0;
      rank += (v.z < projv || (v.z == projv && qb + 2 < p)) ? 1 : 0;
      rank += (v.w < projv || (v.w == projv && qb + 3 < p)) ? 1 : 0;
    }

    // ---- logpdf at sorted slot; accumulate exp into wsum by slot (half0 only) ----
    if (!half) {
      float lpv = lpP[0][p] + lpP[1][p];
      float xp = bp0;
      #pragma unroll
      for (int i = 0; i < NIN1; ++i) xp = fmaf(xs_s[i], Wp[NH + i], xp);
      wsum_s[rank] += __expf(lpv + xp);    // ranks form a permutation -> race-free
    }

    // ---- sorted scatter: write new h directly at ranked row ----
    {
      float* dst = &hBuf[rank * NHP + kbase];
      float4 v;
      v.x = hr0[0]; v.y = hr0[1]; v.z = hr0[2]; v.w = hr0[3]; *(float4*)&dst[0]  = v;
      v.x = hr0[4]; v.y = hr0[5]; v.z = hr0[6]; v.w = hr0[7]; *(float4*)&dst[4]  = v;
      v.x = hr1[0]; v.y = hr1[1]; v.z = hr1[2]; v.w = hr1[3]; *(float4*)&dst[8]  = v;
      v.x = hr1[4]; v.y = hr1[5]; v.z = hr1[6]; v.w = hr1[7]; *(float4*)&dst[12] = v;
      v.x = hr2[0]; v.y = hr2[1]; v.z = hr2[2]; v.w = hr2[3]; *(float4*)&dst[16] = v;
      v.x = hr2[4]; v.y = hr2[5]; v.z = hr2[6]; v.w = hr2[7]; *(float4*)&dst[20] = v;
      v.x = hr3[0]; v.y = hr3[1]; v.z = hr3[2]; v.w = hr3[3]; *(float4*)&dst[24] = v;
      v.x = hr3[4]; v.y = hr3[5]; v.z = hr3[6]; v.w = hr3[7]; *(float4*)&dst[28] = v;
    }
    __syncthreads();
  }

  // ---- epilogue: y_pred[b] = mean_p(h_fin) @ Wf + bf ----
  {
    float s = 0.0f;
    const int p0 = wid * 32;
    #pragma unroll
    for (int pp = 0; pp < 32; ++pp) s += hBuf[(p0 + pp) * NHP + j_a];
    red8_s[wid][j_a] = s;
  }
  __syncthreads();
  if (tid < NH) {
    float hm = 0.0f;
    #pragma unroll
    for (int w = 0; w < 8; ++w) hm += red8_s[w][tid];
    hm *= (1.0f / NP);
    float contrib = hm * Wf[tid];
    contrib += __shfl_xor(contrib, 32, 64);
    contrib += __shfl_xor(contrib, 16, 64);
    contrib += __shfl_xor(contrib, 8, 64);
    contrib += __shfl_xor(contrib, 4, 64);
    contrib += __shfl_xor(contrib, 2, 64);
    contrib += __shfl_xor(contrib, 1, 64);
    if (tid == 0) out[b] = contrib + bf0;
  }
  if (tid < NP) gw[(size_t)tid * NB + b] = wsum_s[tid];
}

// weights[i] = (1/256) * sum_{j<256} gw[(i>>1)*512 + (i&1)*256 + j]
__global__ __launch_bounds__(64, 1)
void pf_weights(const float* __restrict__ gw, float* __restrict__ out) {
  int i = blockIdx.x;
  int lane = threadIdx.x;
  const float* src = gw + ((size_t)(i >> 1)) * NB + (size_t)(i & 1) * NP;
  float4 v = ((const float4*)src)[lane];
  float s = (v.x + v.y) + (v.z + v.w);
  s += __shfl_xor(s, 32, 64);
  s += __shfl_xor(s, 16, 64);
  s += __shfl_xor(s, 8, 64);
  s += __shfl_xor(s, 4, 64);
  s += __shfl_xor(s, 2, 64);
  s += __shfl_xor(s, 1, 64);
  if (lane == 0) out[NB + i] = s * (1.0f / NP);
}

extern "C" void kernel_launch(void* const* d_in, const int* in_sizes, int n_in,
                              void* d_out, int out_size, void* d_ws, size_t ws_size,
                              hipStream_t stream) {
  (void)in_sizes; (void)n_in; (void)out_size; (void)ws_size;
  const float* input_data = (const float*)d_in[0];
  const float* y_prev     = (const float*)d_in[1];
  const float* Wv         = (const float*)d_in[2];
  const float* bv         = (const float*)d_in[3];
  const float* W_ih       = (const float*)d_in[4];
  const float* W_hh       = (const float*)d_in[5];
  const float* b_ih       = (const float*)d_in[6];
  const float* b_hh       = (const float*)d_in[7];
  const float* Wp         = (const float*)d_in[8];
  const float* bp         = (const float*)d_in[9];
  const float* Wf         = (const float*)d_in[10];
  const float* bf         = (const float*)d_in[11];
  float* out  = (float*)d_out;
  float* cbuf = (float*)d_ws;                          // [B][H][P] f32 = 33.5 MB
  float* gw   = cbuf + (size_t)NB * NH * NP;           // [P][B] f32 = 512 KB

  FKeys fk;
  for (int t = 0; t < NT; ++t) {
    uint32_t x0 = 0u, x1 = (uint32_t)t;
    threefry2x32(0u, 1234u, x0, x1);
    fk.a[t] = x0; fk.b[t] = x1;
  }

  pf_main<<<dim3(NB), dim3(NTHR), 0, stream>>>(
      input_data, y_prev, Wv, bv, W_ih, W_hh, b_ih, b_hh, Wp, bp, Wf, bf,
      out, cbuf, gw, fk);
  pf_weights<<<dim3(NB), dim3(64), 0, stream>>>(gw, out);
}

// Round 5
// 3202.808 us; speedup vs baseline: 4.1949x; 2.6624x over previous
//
#include <hip/hip_runtime.h>
#include <stdint.h>

#define NB 512   // batch
#define NT 32    // time steps
#define NIN 8    // input feats
#define NIN1 9   // + y_prev
#define NH 64    // hidden
#define NP 256   // particles
#define NTHR 512 // 8 waves: wave w owns gate-rows r' in [32w, 32w+32)
#define HROW 72  // padded hbf row stride in bf16 (144 B, 16B-aligned)

typedef __attribute__((ext_vector_type(8))) short bf16x8;
typedef __attribute__((ext_vector_type(16))) float f32x16;

struct FKeys { uint32_t a[NT]; uint32_t b[NT]; };

// ---------------- Threefry-2x32-20 (exact JAX semantics) ----------------
__host__ __device__ __forceinline__ void tfr(uint32_t& x0, uint32_t& x1, int r) {
  x0 += x1; x1 = (x1 << r) | (x1 >> (32 - r)); x1 ^= x0;
}

__host__ __device__ __forceinline__ void threefry2x32(uint32_t k0, uint32_t k1,
                                                      uint32_t& x0, uint32_t& x1) {
  uint32_t k2 = k0 ^ k1 ^ 0x1BD11BDAu;
  x0 += k0; x1 += k1;
  tfr(x0,x1,13); tfr(x0,x1,15); tfr(x0,x1,26); tfr(x0,x1,6);
  x0 += k1; x1 += k2 + 1u;
  tfr(x0,x1,17); tfr(x0,x1,29); tfr(x0,x1,16); tfr(x0,x1,24);
  x0 += k2; x1 += k0 + 2u;
  tfr(x0,x1,13); tfr(x0,x1,15); tfr(x0,x1,26); tfr(x0,x1,6);
  x0 += k0; x1 += k1 + 3u;
  tfr(x0,x1,17); tfr(x0,x1,29); tfr(x0,x1,16); tfr(x0,x1,24);
  x0 += k1; x1 += k2 + 4u;
  tfr(x0,x1,13); tfr(x0,x1,15); tfr(x0,x1,26); tfr(x0,x1,6);
  x0 += k2; x1 += k0 + 5u;
}

// bits -> uniform -> sqrt(2)*erfinv  (XLA f32 path) — keep EXACT
__device__ __forceinline__ float normal_from_bits(uint32_t bits) {
  float f = __uint_as_float((bits >> 9) | 0x3f800000u) - 1.0f;
  const float lo = -0.99999994f;
  float u = fmaxf(lo, fmaf(f, 2.0f, lo));
  float w = -log1pf(-u * u);
  float p;
  if (w < 5.0f) {
    w -= 2.5f;
    p = 2.81022636e-08f;
    p = fmaf(p, w, 3.43273939e-07f);
    p = fmaf(p, w, -3.5233877e-06f);
    p = fmaf(p, w, -4.39150654e-06f);
    p = fmaf(p, w, 0.00021858087f);
    p = fmaf(p, w, -0.00125372503f);
    p = fmaf(p, w, -0.00417768164f);
    p = fmaf(p, w, 0.246640727f);
    p = fmaf(p, w, 1.50140941f);
  } else {
    w = sqrtf(w) - 3.0f;
    p = -0.000200214257f;
    p = fmaf(p, w, 0.000100950558f);
    p = fmaf(p, w, 0.00134934322f);
    p = fmaf(p, w, -0.00367342844f);
    p = fmaf(p, w, 0.00573950773f);
    p = fmaf(p, w, -0.0076224613f);
    p = fmaf(p, w, 0.00943887047f);
    p = fmaf(p, w, 1.00167406f);
    p = fmaf(p, w, 2.83297682f);
  }
  return 1.41421356f * (p * u);
}

__device__ __forceinline__ float frcp(float x) { return __builtin_amdgcn_rcpf(x); }
__device__ __forceinline__ float fsigmoid(float x) { return frcp(1.0f + __expf(-x)); }
__device__ __forceinline__ float ftanh(float x) { return 1.0f - 2.0f * frcp(1.0f + __expf(2.0f * x)); }

__device__ __forceinline__ uint16_t bf16_rne(float f) {
  uint32_t u = __float_as_uint(f);
  return (uint16_t)((u + 0x7FFFu + ((u >> 16) & 1u)) >> 16);
}
__device__ __forceinline__ float bf16_to_f(uint16_t s) {
  return __uint_as_float(((uint32_t)s) << 16);
}

// ---------------- main kernel: one block (512 thr) per batch elem ----------------
// Gates GEMM per step: D[r'][p] = sum_j W'[r'][j] * h[p][j], r' = 4k+gate.
// A = W' (3-way bf16 split, registers, loaded once). B = h (bf16 splits in LDS).
// D fragment: lane l of wave w holds the 4 gates of cells (p = 32m+(l&31),
// k = 8w+2q+(l>>5)) in acc[4q..4q+3]. Elementwise runs on fragments directly.
__global__ __launch_bounds__(NTHR, 2)
void pf_main(const float* __restrict__ input_data, const float* __restrict__ y_prev,
             const float* __restrict__ Wv, const float* __restrict__ bv,
             const float* __restrict__ W_ih, const float* __restrict__ W_hh,
             const float* __restrict__ b_ih, const float* __restrict__ b_hh,
             const float* __restrict__ Wp, const float* __restrict__ bp,
             const float* __restrict__ Wf, const float* __restrict__ bf,
             float* __restrict__ out, float* __restrict__ cbuf, float* __restrict__ gw,
             FKeys fk)
{
  __shared__ __align__(16) short hbf_hi[NP * HROW];   // 36.9 KB
  __shared__ __align__(16) short hbf_mid[NP * HROW];  // 36.9 KB
  __shared__ __align__(16) short hbf_lo[NP * HROW];   // 36.9 KB
  __shared__ float2 pp_s[8 * NP];                     // 16.4 KB (proj, lp) partials per wave
  __shared__ __align__(16) float xg_s[NP];            // x-part of gate-row r'
  __shared__ __align__(16) float projC[NP];
  __shared__ float wsum_s[NP];
  __shared__ float hsum_s[NH];
  __shared__ float std_s[NH];
  __shared__ float xs_s[16];

  const int tid  = threadIdx.x;
  const int b    = blockIdx.x;
  const int lane = tid & 63;
  const int w    = tid >> 6;          // wave 0..7
  const int ln31 = lane & 31;
  const int h5   = lane >> 5;         // 0/1

  // ---- one-time init ----
  for (int idx = tid; idx < NP * HROW; idx += NTHR) {
    hbf_hi[idx] = 0; hbf_mid[idx] = 0; hbf_lo[idx] = 0;
  }
  if (tid < NH) hsum_s[tid] = 0.0f;
  if (tid < NP) wsum_s[tid] = 0.0f;

  // ---- per-lane constants ----
  const float bf0 = bf[0];
  const float bp0 = bp[0];
  const uint32_t bsh = (uint32_t)b << 6;

  // W' A-fragments (3-way split), loaded ONCE: r' = 32w + ln31, orig row = (r'&3)*64 + (r'>>2)
  const int rp   = 32 * w + ln31;
  const int orig = (rp & 3) * NH + (rp >> 2);
  bf16x8 wA_hi[4], wA_mid[4], wA_lo[4];
  #pragma unroll
  for (int kt = 0; kt < 4; ++kt) {
    const int j0 = kt * 16 + h5 * 8;
    #pragma unroll
    for (int e = 0; e < 8; ++e) {
      float x = W_hh[orig * NH + j0 + e];
      uint16_t uh = bf16_rne(x);              float fh = bf16_to_f(uh);
      uint16_t um = bf16_rne(x - fh);         float fm = bf16_to_f(um);
      uint16_t ul = bf16_rne(x - fh - fm);
      wA_hi[kt][e]  = (short)uh;
      wA_mid[kt][e] = (short)um;
      wA_lo[kt][e]  = (short)ul;
    }
  }

  // per-lane k constants: k_q = 8w + 2q + h5
  float wf_r[4], wp_r[4];
  #pragma unroll
  for (int q = 0; q < 4; ++q) {
    const int kq = 8 * w + 2 * q + h5;
    wf_r[q] = Wf[kq];
    wp_r[q] = Wp[kq];
  }
  float wpx[NIN1];
  #pragma unroll
  for (int i = 0; i < NIN1; ++i) wpx[i] = Wp[NH + i];

  // x-part weights for gate-row r' = tid (reordered)
  float wih_r[NIN1];
  float bihh = 0.0f;
  if (tid < NP) {
    const int orow = (tid & 3) * NH + (tid >> 2);
    #pragma unroll
    for (int i = 0; i < NIN1; ++i) wih_r[i] = W_ih[orow * NIN1 + i];
    bihh = b_ih[orow] + b_hh[orow];
  }
  const float bv_r = (tid < NH) ? bv[tid] : 0.0f;

  const size_t cb0 = ((size_t)b * NH + 8 * w + h5) * NP + ln31;  // + 512*q + 32*mm (+128 for B-tile)

  __syncthreads();

  for (int t = 0; t < NT; ++t) {
    if (tid < NIN) xs_s[tid] = input_data[(b * NT + t) * NIN + tid];
    if (tid == NIN) xs_s[NIN] = y_prev[b * NT + t];
    __syncthreads();   // b1: xs, sorted hbf(t-1), hsum(t-1) ready

    // ---- phase 1: std (tid<64) and xg (tid<256) ----
    if (tid < NH) {
      float v = bv_r;
      const float* wvr = Wv + tid * (NIN1 + NH);
      #pragma unroll
      for (int i = 0; i < NIN1; ++i) v = fmaf(xs_s[i], wvr[i], v);
      #pragma unroll
      for (int k = 0; k < NH; ++k) v = fmaf(hsum_s[k] * (1.0f / NP), wvr[NIN1 + k], v);
      std_s[tid] = fmaxf(v, 0.0f) + log1pf(expf(-fabsf(v)));   // softplus, libm exact
    }
    if (tid < NP) {
      float a = bihh;
      #pragma unroll
      for (int i = 0; i < NIN1; ++i) a = fmaf(xs_s[i], wih_r[i], a);
      xg_s[tid] = a;
    }
    __syncthreads();   // b2

    // ---- per-step per-lane preloads ----
    float xg_reg[16];
    #pragma unroll
    for (int rq = 0; rq < 4; ++rq) {
      const float4 v = *(const float4*)&xg_s[32 * w + 8 * rq + 4 * h5];
      xg_reg[rq * 4 + 0] = v.x; xg_reg[rq * 4 + 1] = v.y;
      xg_reg[rq * 4 + 2] = v.z; xg_reg[rq * 4 + 3] = v.w;
    }
    float std_r[4];
    #pragma unroll
    for (int q = 0; q < 4; ++q) std_r[q] = std_s[8 * w + 2 * q + h5];

    // ---- phase 2a: MFMA + elementwise, tile pairs (mm, mm+4) ----
    const uint32_t fk0 = fk.a[t], fk1 = fk.b[t];
    const bool t0 = (t == 0);
    float hs[4] = {0.0f, 0.0f, 0.0f, 0.0f};
    float hrA_st[4][4], hrB_st[4][4];

    #pragma unroll
    for (int mm = 0; mm < 4; ++mm) {
      const int pA = mm * 32 + ln31;      // tile A particle (0..127)
      const int pB = pA + 128;            // tile B particle
      const size_t cbA = cb0 + (size_t)mm * 32;

      float coldA[4], coldB[4];
      #pragma unroll
      for (int q = 0; q < 4; ++q) {
        coldA[q] = cbuf[cbA + (size_t)q * 512];
        coldB[q] = cbuf[cbA + (size_t)q * 512 + 128];
      }

      f32x16 accA, accB;
      #pragma unroll
      for (int r = 0; r < 16; ++r) { accA[r] = xg_reg[r]; accB[r] = xg_reg[r]; }

      #pragma unroll
      for (int kt = 0; kt < 4; ++kt) {
        const int off = kt * 16 + h5 * 8;
        const bf16x8 bAh = *(const bf16x8*)&hbf_hi [pA * HROW + off];
        const bf16x8 bAm = *(const bf16x8*)&hbf_mid[pA * HROW + off];
        const bf16x8 bAl = *(const bf16x8*)&hbf_lo [pA * HROW + off];
        const bf16x8 bBh = *(const bf16x8*)&hbf_hi [pB * HROW + off];
        const bf16x8 bBm = *(const bf16x8*)&hbf_mid[pB * HROW + off];
        const bf16x8 bBl = *(const bf16x8*)&hbf_lo [pB * HROW + off];
        accA = __builtin_amdgcn_mfma_f32_32x32x16_bf16(wA_hi[kt],  bAh, accA, 0, 0, 0);
        accA = __builtin_amdgcn_mfma_f32_32x32x16_bf16(wA_hi[kt],  bAm, accA, 0, 0, 0);
        accA = __builtin_amdgcn_mfma_f32_32x32x16_bf16(wA_mid[kt], bAh, accA, 0, 0, 0);
        accA = __builtin_amdgcn_mfma_f32_32x32x16_bf16(wA_hi[kt],  bAl, accA, 0, 0, 0);
        accA = __builtin_amdgcn_mfma_f32_32x32x16_bf16(wA_lo[kt],  bAh, accA, 0, 0, 0);
        accA = __builtin_amdgcn_mfma_f32_32x32x16_bf16(wA_mid[kt], bAm, accA, 0, 0, 0);
        accB = __builtin_amdgcn_mfma_f32_32x32x16_bf16(wA_hi[kt],  bBh, accB, 0, 0, 0);
        accB = __builtin_amdgcn_mfma_f32_32x32x16_bf16(wA_hi[kt],  bBm, accB, 0, 0, 0);
        accB = __builtin_amdgcn_mfma_f32_32x32x16_bf16(wA_mid[kt], bBh, accB, 0, 0, 0);
        accB = __builtin_amdgcn_mfma_f32_32x32x16_bf16(wA_hi[kt],  bBl, accB, 0, 0, 0);
        accB = __builtin_amdgcn_mfma_f32_32x32x16_bf16(wA_lo[kt],  bBh, accB, 0, 0, 0);
        accB = __builtin_amdgcn_mfma_f32_32x32x16_bf16(wA_mid[kt], bBm, accB, 0, 0, 0);
      }

      float plA = 0.0f, lpA = 0.0f, plB = 0.0f, lpB = 0.0f;
      #pragma unroll
      for (int q = 0; q < 4; ++q) {
        const int kq = 8 * w + 2 * q + h5;
        // --- tile A cell ---
        float cpA = t0 ? 0.0f : coldA[q];
        float siA = fsigmoid(accA[4 * q + 0]);
        float sfA = fsigmoid(accA[4 * q + 1]);
        float soA = fsigmoid(accA[4 * q + 3]);
        float cnA = sfA * cpA + siA * ftanh(accA[4 * q + 2]);
        cbuf[cbA + (size_t)q * 512] = cnA;
        float hlA = soA * ftanh(cnA);
        // --- tile B cell ---
        float cpB = t0 ? 0.0f : coldB[q];
        float siB = fsigmoid(accB[4 * q + 0]);
        float sfB = fsigmoid(accB[4 * q + 1]);
        float soB = fsigmoid(accB[4 * q + 3]);
        float cnB = sfB * cpB + siB * ftanh(accB[4 * q + 2]);
        cbuf[cbA + (size_t)q * 512 + 128] = cnB;
        float hlB = soB * ftanh(cnB);
        // --- shared threefry: pair (idx, idx + 2^22) = particles (pA, pA+128) ---
        uint32_t x0 = ((uint32_t)pA << 15) | bsh | (uint32_t)kq;
        uint32_t x1 = x0 + (1u << 22);
        threefry2x32(fk0, fk1, x0, x1);
        float eA = normal_from_bits(x0);
        float eB = normal_from_bits(x1);
        float hrA = fmaf(eA, std_r[q], hlA);
        float hrB = fmaf(eB, std_r[q], hlB);
        hrA_st[mm][q] = hrA;
        hrB_st[mm][q] = hrB;
        hs[q] += hrA + hrB;
        plA = fmaf(hrA, wf_r[q], plA); lpA = fmaf(hrA, wp_r[q], lpA);
        plB = fmaf(hrB, wf_r[q], plB); lpB = fmaf(hrB, wp_r[q], lpB);
      }
      plA += __shfl_xor(plA, 32, 64); lpA += __shfl_xor(lpA, 32, 64);
      plB += __shfl_xor(plB, 32, 64); lpB += __shfl_xor(lpB, 32, 64);
      if (lane < 32) {
        pp_s[w * NP + pA] = make_float2(plA, lpA);
        pp_s[w * NP + pB] = make_float2(plB, lpB);
      }
    }

    // hsum: reduce over 32-lane groups; k = 8w + 2q + h5 (both halves distinct)
    #pragma unroll
    for (int q = 0; q < 4; ++q) {
      float s = hs[q];
      s += __shfl_xor(s, 1, 64); s += __shfl_xor(s, 2, 64); s += __shfl_xor(s, 4, 64);
      s += __shfl_xor(s, 8, 64); s += __shfl_xor(s, 16, 64);
      if (ln31 == q) hsum_s[8 * w + 2 * q + h5] = s;
    }
    __syncthreads();   // b3: all MFMA reads of hbf done; pp_s complete

    // ---- phase 2b: write new h (unsorted rows) as bf16 splits ----
    #pragma unroll
    for (int mm = 0; mm < 4; ++mm) {
      const int pA = mm * 32 + ln31;
      #pragma unroll
      for (int q = 0; q < 4; ++q) {
        const int kq = 8 * w + 2 * q + h5;
        {
          float x = hrA_st[mm][q];
          uint16_t uh = bf16_rne(x);      float fh = bf16_to_f(uh);
          uint16_t um = bf16_rne(x - fh); float fm = bf16_to_f(um);
          uint16_t ul = bf16_rne(x - fh - fm);
          hbf_hi [pA * HROW + kq] = (short)uh;
          hbf_mid[pA * HROW + kq] = (short)um;
          hbf_lo [pA * HROW + kq] = (short)ul;
        }
        {
          float x = hrB_st[mm][q];
          uint16_t uh = bf16_rne(x);      float fh = bf16_to_f(uh);
          uint16_t um = bf16_rne(x - fh); float fm = bf16_to_f(um);
          uint16_t ul = bf16_rne(x - fh - fm);
          hbf_hi [(pA + 128) * HROW + kq] = (short)uh;
          hbf_mid[(pA + 128) * HROW + kq] = (short)um;
          hbf_lo [(pA + 128) * HROW + kq] = (short)ul;
        }
      }
    }
    float lpv = 0.0f;
    if (tid < NP) {
      float pv = bf0;
      #pragma unroll
      for (int ww = 0; ww < 8; ++ww) {
        float2 v = pp_s[ww * NP + tid];
        pv += v.x; lpv += v.y;
      }
      projC[tid] = pv;
    }
    __syncthreads();   // b4: projC + unsorted hbf ready

    // ---- phase 3: rank + wsum + permute-read (tid < 256) ----
    int rank = 0;
    int4 rowh[8], rowm[8], rowl[8];
    if (tid < NP) {
      const float projv = projC[tid];
      const float4* c4 = (const float4*)projC;
      #pragma unroll 8
      for (int q4 = 0; q4 < NP / 4; ++q4) {
        float4 v = c4[q4];
        int qb = q4 * 4;
        rank += (v.x < projv || (v.x == projv && qb + 0 < tid)) ? 1 : 0;
        rank += (v.y < projv || (v.y == projv && qb + 1 < tid)) ? 1 : 0;
        rank += (v.z < projv || (v.z == projv && qb + 2 < tid)) ? 1 : 0;
        rank += (v.w < projv || (v.w == projv && qb + 3 < tid)) ? 1 : 0;
      }
      float xp = bp0;
      #pragma unroll
      for (int i = 0; i < NIN1; ++i) xp = fmaf(xs_s[i], wpx[i], xp);
      wsum_s[rank] += __expf(lpv + xp);   // ranks form a permutation -> race-free
      #pragma unroll
      for (int c = 0; c < 8; ++c) {
        rowh[c] = *(const int4*)&hbf_hi [tid * HROW + c * 8];
        rowm[c] = *(const int4*)&hbf_mid[tid * HROW + c * 8];
        rowl[c] = *(const int4*)&hbf_lo [tid * HROW + c * 8];
      }
    }
    __syncthreads();   // b5: permute reads done
    if (tid < NP) {
      #pragma unroll
      for (int c = 0; c < 8; ++c) {
        *(int4*)&hbf_hi [rank * HROW + c * 8] = rowh[c];
        *(int4*)&hbf_mid[rank * HROW + c * 8] = rowm[c];
        *(int4*)&hbf_lo [rank * HROW + c * 8] = rowl[c];
      }
    }
    // loop-top barrier (b1) separates permute-writes from next step's reads
  }

  __syncthreads();
  // ---- epilogue: y_pred[b] = mean_p(h_fin) @ Wf + bf ----
  if (tid < NH) {
    float contrib = (hsum_s[tid] * (1.0f / NP)) * Wf[tid];
    contrib += __shfl_xor(contrib, 32, 64);
    contrib += __shfl_xor(contrib, 16, 64);
    contrib += __shfl_xor(contrib, 8, 64);
    contrib += __shfl_xor(contrib, 4, 64);
    contrib += __shfl_xor(contrib, 2, 64);
    contrib += __shfl_xor(contrib, 1, 64);
    if (tid == 0) out[b] = contrib + bf0;
  }
  if (tid < NP) gw[(size_t)tid * NB + b] = wsum_s[tid];
}

// weights[i] = (1/256) * sum_{j<256} gw[(i>>1)*512 + (i&1)*256 + j]
__global__ __launch_bounds__(64, 1)
void pf_weights(const float* __restrict__ gw, float* __restrict__ out) {
  int i = blockIdx.x;
  int lane = threadIdx.x;
  const float* src = gw + ((size_t)(i >> 1)) * NB + (size_t)(i & 1) * NP;
  float4 v = ((const float4*)src)[lane];
  float s = (v.x + v.y) + (v.z + v.w);
  s += __shfl_xor(s, 32, 64);
  s += __shfl_xor(s, 16, 64);
  s += __shfl_xor(s, 8, 64);
  s += __shfl_xor(s, 4, 64);
  s += __shfl_xor(s, 2, 64);
  s += __shfl_xor(s, 1, 64);
  if (lane == 0) out[NB + i] = s * (1.0f / NP);
}

extern "C" void kernel_launch(void* const* d_in, const int* in_sizes, int n_in,
                              void* d_out, int out_size, void* d_ws, size_t ws_size,
                              hipStream_t stream) {
  (void)in_sizes; (void)n_in; (void)out_size; (void)ws_size;
  const float* input_data = (const float*)d_in[0];
  const float* y_prev     = (const float*)d_in[1];
  const float* Wv         = (const float*)d_in[2];
  const float* bv         = (const float*)d_in[3];
  const float* W_ih       = (const float*)d_in[4];
  const float* W_hh       = (const float*)d_in[5];
  const float* b_ih       = (const float*)d_in[6];
  const float* b_hh       = (const float*)d_in[7];
  const float* Wp         = (const float*)d_in[8];
  const float* bp         = (const float*)d_in[9];
  const float* Wf         = (const float*)d_in[10];
  const float* bf         = (const float*)d_in[11];
  float* out  = (float*)d_out;
  float* cbuf = (float*)d_ws;                          // [B][H][P] f32 = 33.5 MB
  float* gw   = cbuf + (size_t)NB * NH * NP;           // [P][B] f32 = 512 KB

  FKeys fk;
  for (int t = 0; t < NT; ++t) {
    uint32_t x0 = 0u, x1 = (uint32_t)t;
    threefry2x32(0u, 1234u, x0, x1);
    fk.a[t] = x0; fk.b[t] = x1;
  }

  pf_main<<<dim3(NB), dim3(NTHR), 0, stream>>>(
      input_data, y_prev, Wv, bv, W_ih, W_hh, b_ih, b_hh, Wp, bp, Wf, bf,
      out, cbuf, gw, fk);
  pf_weights<<<dim3(NB), dim3(64), 0, stream>>>(gw, out);
}

// Round 6
// 2357.299 us; speedup vs baseline: 5.6995x; 1.3587x over previous
//
#include <hip/hip_runtime.h>
#include <stdint.h>

#define NB 512   // batch
#define NT 32    // time steps
#define NIN 8    // input feats
#define NIN1 9   // + y_prev
#define NH 64    // hidden
#define NP 256   // particles
#define NTHR 512 // 8 waves: wave w owns gate-rows r' in [32w, 32w+32)
#define HROW 68  // bf16 row stride: 136 B = 34 dwords -> 2-way bank alias (free)

typedef __attribute__((ext_vector_type(8))) short bf16x8;
typedef __attribute__((ext_vector_type(16))) float f32x16;

struct FKeys { uint32_t a[NT]; uint32_t b[NT]; };

// ---------------- Threefry-2x32-20 (exact JAX semantics) ----------------
__host__ __device__ __forceinline__ void tfr(uint32_t& x0, uint32_t& x1, int r) {
  x0 += x1; x1 = (x1 << r) | (x1 >> (32 - r)); x1 ^= x0;
}

__host__ __device__ __forceinline__ void threefry2x32(uint32_t k0, uint32_t k1,
                                                      uint32_t& x0, uint32_t& x1) {
  uint32_t k2 = k0 ^ k1 ^ 0x1BD11BDAu;
  x0 += k0; x1 += k1;
  tfr(x0,x1,13); tfr(x0,x1,15); tfr(x0,x1,26); tfr(x0,x1,6);
  x0 += k1; x1 += k2 + 1u;
  tfr(x0,x1,17); tfr(x0,x1,29); tfr(x0,x1,16); tfr(x0,x1,24);
  x0 += k2; x1 += k0 + 2u;
  tfr(x0,x1,13); tfr(x0,x1,15); tfr(x0,x1,26); tfr(x0,x1,6);
  x0 += k0; x1 += k1 + 3u;
  tfr(x0,x1,17); tfr(x0,x1,29); tfr(x0,x1,16); tfr(x0,x1,24);
  x0 += k1; x1 += k2 + 4u;
  tfr(x0,x1,13); tfr(x0,x1,15); tfr(x0,x1,26); tfr(x0,x1,6);
  x0 += k2; x1 += k0 + 5u;
}

// bits -> uniform -> sqrt(2)*erfinv  (XLA f32 path) — keep EXACT
__device__ __forceinline__ float normal_from_bits(uint32_t bits) {
  float f = __uint_as_float((bits >> 9) | 0x3f800000u) - 1.0f;
  const float lo = -0.99999994f;
  float u = fmaxf(lo, fmaf(f, 2.0f, lo));
  float w = -log1pf(-u * u);
  float p;
  if (w < 5.0f) {
    w -= 2.5f;
    p = 2.81022636e-08f;
    p = fmaf(p, w, 3.43273939e-07f);
    p = fmaf(p, w, -3.5233877e-06f);
    p = fmaf(p, w, -4.39150654e-06f);
    p = fmaf(p, w, 0.00021858087f);
    p = fmaf(p, w, -0.00125372503f);
    p = fmaf(p, w, -0.00417768164f);
    p = fmaf(p, w, 0.246640727f);
    p = fmaf(p, w, 1.50140941f);
  } else {
    w = sqrtf(w) - 3.0f;
    p = -0.000200214257f;
    p = fmaf(p, w, 0.000100950558f);
    p = fmaf(p, w, 0.00134934322f);
    p = fmaf(p, w, -0.00367342844f);
    p = fmaf(p, w, 0.00573950773f);
    p = fmaf(p, w, -0.0076224613f);
    p = fmaf(p, w, 0.00943887047f);
    p = fmaf(p, w, 1.00167406f);
    p = fmaf(p, w, 2.83297682f);
  }
  return 1.41421356f * (p * u);
}

__device__ __forceinline__ float frcp(float x) { return __builtin_amdgcn_rcpf(x); }
__device__ __forceinline__ float fsigmoid(float x) { return frcp(1.0f + __expf(-x)); }
__device__ __forceinline__ float ftanh(float x) { return 1.0f - 2.0f * frcp(1.0f + __expf(2.0f * x)); }

__device__ __forceinline__ uint16_t bf16_rne(float f) {
  uint32_t u = __float_as_uint(f);
  return (uint16_t)((u + 0x7FFFu + ((u >> 16) & 1u)) >> 16);
}
__device__ __forceinline__ float bf16_to_f(uint16_t s) {
  return __uint_as_float(((uint32_t)s) << 16);
}

// 8B-aligned LDS bf16x8 load (two ds_read_b64, conflict-free at HROW=68)
__device__ __forceinline__ bf16x8 lds_ld8(const short* p) {
  union { bf16x8 v; uint64_t q[2]; } u;
  u.q[0] = *(const uint64_t*)(p);
  u.q[1] = *(const uint64_t*)(p + 4);
  return u.v;
}

// ---------------- main kernel: one block (512 thr) per batch elem ----------------
// Gates GEMM per step: D[r'][p] = sum_j W'[r'][j] * h[p][j], r' = 4k+gate.
// A = W' (3-way bf16 split, registers, loaded once). B = h (bf16 splits in LDS).
// Lane l of wave w holds the 4 gates of cells (p = 32m+(l&31), k = 8w+2q+(l>>5))
// in acc[4q..4q+3]; c for those cells lives in registers (ownership is static).
__global__ __launch_bounds__(NTHR, 2)
void pf_main(const float* __restrict__ input_data, const float* __restrict__ y_prev,
             const float* __restrict__ Wv, const float* __restrict__ bv,
             const float* __restrict__ W_ih, const float* __restrict__ W_hh,
             const float* __restrict__ b_ih, const float* __restrict__ b_hh,
             const float* __restrict__ Wp, const float* __restrict__ bp,
             const float* __restrict__ Wf, const float* __restrict__ bf,
             float* __restrict__ out, float* __restrict__ gw,
             FKeys fk)
{
  __shared__ __align__(16) short hbf_hi[NP * HROW];   // 34.8 KB
  __shared__ __align__(16) short hbf_mid[NP * HROW];  // 34.8 KB
  __shared__ __align__(16) short hbf_lo[NP * HROW];   // 34.8 KB
  __shared__ float2 pp_s[8 * NP];                     // 16.4 KB (proj, lp) per-wave partials
  __shared__ __align__(16) float xg_s[NP];            // x-part of gate-row r'
  __shared__ __align__(16) float projC[NP];
  __shared__ float wsum_s[NP];
  __shared__ int   rankP_s[2 * NP];
  __shared__ float hsum_s[NH];
  __shared__ float std_s[NH];
  __shared__ float xs_s[16];

  const int tid  = threadIdx.x;
  const int b    = blockIdx.x;
  const int lane = tid & 63;
  const int w    = tid >> 6;          // wave 0..7
  const int ln31 = lane & 31;
  const int h5   = lane >> 5;         // 0/1
  const int ph   = tid & (NP - 1);    // particle for rank/permute phases
  const int hh   = tid >> 8;          // half index for rank/permute split

  // ---- one-time init ----
  for (int idx = tid; idx < NP * HROW; idx += NTHR) {
    hbf_hi[idx] = 0; hbf_mid[idx] = 0; hbf_lo[idx] = 0;
  }
  if (tid < NH) hsum_s[tid] = 0.0f;
  if (tid < NP) wsum_s[tid] = 0.0f;

  const float bf0 = bf[0];
  const float bp0 = bp[0];
  const uint32_t bsh = (uint32_t)b << 6;

  // W' A-fragments (3-way split), loaded ONCE: r' = 32w + ln31, orig row = (r'&3)*64 + (r'>>2)
  const int rp   = 32 * w + ln31;
  const int orig = (rp & 3) * NH + (rp >> 2);
  bf16x8 wA_hi[4], wA_mid[4], wA_lo[4];
  #pragma unroll
  for (int kt = 0; kt < 4; ++kt) {
    const int j0 = kt * 16 + h5 * 8;
    #pragma unroll
    for (int e = 0; e < 8; ++e) {
      float x = W_hh[orig * NH + j0 + e];
      uint16_t uh = bf16_rne(x);              float fh = bf16_to_f(uh);
      uint16_t um = bf16_rne(x - fh);         float fm = bf16_to_f(um);
      uint16_t ul = bf16_rne(x - fh - fm);
      wA_hi[kt][e]  = (short)uh;
      wA_mid[kt][e] = (short)um;
      wA_lo[kt][e]  = (short)ul;
    }
  }

  float wf_r[4], wp_r[4];
  #pragma unroll
  for (int q = 0; q < 4; ++q) {
    const int kq = 8 * w + 2 * q + h5;
    wf_r[q] = Wf[kq];
    wp_r[q] = Wp[kq];
  }
  float wpx[NIN1];
  #pragma unroll
  for (int i = 0; i < NIN1; ++i) wpx[i] = Wp[NH + i];

  float wih_r[NIN1];
  float bihh = 0.0f;
  if (tid < NP) {
    const int orow = (tid & 3) * NH + (tid >> 2);
    #pragma unroll
    for (int i = 0; i < NIN1; ++i) wih_r[i] = W_ih[orow * NIN1 + i];
    bihh = b_ih[orow] + b_hh[orow];
  }
  const float bv_r = (tid < NH) ? bv[tid] : 0.0f;

  // c state in registers: cells (p = 32mm+ln31 (+128), k = 8w+2q+h5) — static ownership
  float cA[4][4], cB[4][4];
  #pragma unroll
  for (int mm = 0; mm < 4; ++mm) {
    #pragma unroll
    for (int q = 0; q < 4; ++q) { cA[mm][q] = 0.0f; cB[mm][q] = 0.0f; }
  }

  __syncthreads();

  for (int t = 0; t < NT; ++t) {
    if (tid < NIN) xs_s[tid] = input_data[(b * NT + t) * NIN + tid];
    if (tid == NIN) xs_s[NIN] = y_prev[b * NT + t];
    __syncthreads();   // b1: xs, sorted hbf(t-1), hsum(t-1) ready

    // ---- phase 1: std (tid<64) and xg (tid<256) ----
    if (tid < NH) {
      float v = bv_r;
      const float* wvr = Wv + tid * (NIN1 + NH);
      #pragma unroll
      for (int i = 0; i < NIN1; ++i) v = fmaf(xs_s[i], wvr[i], v);
      #pragma unroll
      for (int k = 0; k < NH; ++k) v = fmaf(hsum_s[k] * (1.0f / NP), wvr[NIN1 + k], v);
      std_s[tid] = fmaxf(v, 0.0f) + log1pf(expf(-fabsf(v)));   // softplus, libm exact
    }
    if (tid < NP) {
      float a = bihh;
      #pragma unroll
      for (int i = 0; i < NIN1; ++i) a = fmaf(xs_s[i], wih_r[i], a);
      xg_s[tid] = a;
    }
    __syncthreads();   // b2

    // ---- per-step per-lane preloads ----
    float xg_reg[16];
    #pragma unroll
    for (int rq = 0; rq < 4; ++rq) {
      const float4 v = *(const float4*)&xg_s[32 * w + 8 * rq + 4 * h5];
      xg_reg[rq * 4 + 0] = v.x; xg_reg[rq * 4 + 1] = v.y;
      xg_reg[rq * 4 + 2] = v.z; xg_reg[rq * 4 + 3] = v.w;
    }
    float std_r[4];
    #pragma unroll
    for (int q = 0; q < 4; ++q) std_r[q] = std_s[8 * w + 2 * q + h5];

    // ---- phase 2a: MFMA + elementwise, tile pairs (mm, mm+4) ----
    const uint32_t fk0 = fk.a[t], fk1 = fk.b[t];
    float hs[4] = {0.0f, 0.0f, 0.0f, 0.0f};
    float hrA_st[4][4], hrB_st[4][4];

    #pragma unroll
    for (int mm = 0; mm < 4; ++mm) {
      const int pA = mm * 32 + ln31;      // tile A particle (0..127)
      const int pB = pA + 128;            // tile B particle

      f32x16 accA, accB;
      #pragma unroll
      for (int r = 0; r < 16; ++r) { accA[r] = xg_reg[r]; accB[r] = xg_reg[r]; }

      #pragma unroll
      for (int kt = 0; kt < 4; ++kt) {
        const int off = kt * 16 + h5 * 8;
        const bf16x8 bAh = lds_ld8(&hbf_hi [pA * HROW + off]);
        const bf16x8 bAm = lds_ld8(&hbf_mid[pA * HROW + off]);
        const bf16x8 bAl = lds_ld8(&hbf_lo [pA * HROW + off]);
        const bf16x8 bBh = lds_ld8(&hbf_hi [pB * HROW + off]);
        const bf16x8 bBm = lds_ld8(&hbf_mid[pB * HROW + off]);
        const bf16x8 bBl = lds_ld8(&hbf_lo [pB * HROW + off]);
        accA = __builtin_amdgcn_mfma_f32_32x32x16_bf16(wA_hi[kt],  bAh, accA, 0, 0, 0);
        accA = __builtin_amdgcn_mfma_f32_32x32x16_bf16(wA_hi[kt],  bAm, accA, 0, 0, 0);
        accA = __builtin_amdgcn_mfma_f32_32x32x16_bf16(wA_mid[kt], bAh, accA, 0, 0, 0);
        accA = __builtin_amdgcn_mfma_f32_32x32x16_bf16(wA_hi[kt],  bAl, accA, 0, 0, 0);
        accA = __builtin_amdgcn_mfma_f32_32x32x16_bf16(wA_lo[kt],  bAh, accA, 0, 0, 0);
        accA = __builtin_amdgcn_mfma_f32_32x32x16_bf16(wA_mid[kt], bAm, accA, 0, 0, 0);
        accB = __builtin_amdgcn_mfma_f32_32x32x16_bf16(wA_hi[kt],  bBh, accB, 0, 0, 0);
        accB = __builtin_amdgcn_mfma_f32_32x32x16_bf16(wA_hi[kt],  bBm, accB, 0, 0, 0);
        accB = __builtin_amdgcn_mfma_f32_32x32x16_bf16(wA_mid[kt], bBh, accB, 0, 0, 0);
        accB = __builtin_amdgcn_mfma_f32_32x32x16_bf16(wA_hi[kt],  bBl, accB, 0, 0, 0);
        accB = __builtin_amdgcn_mfma_f32_32x32x16_bf16(wA_lo[kt],  bBh, accB, 0, 0, 0);
        accB = __builtin_amdgcn_mfma_f32_32x32x16_bf16(wA_mid[kt], bBm, accB, 0, 0, 0);
      }

      float plA = 0.0f, lpA = 0.0f, plB = 0.0f, lpB = 0.0f;
      #pragma unroll
      for (int q = 0; q < 4; ++q) {
        const int kq = 8 * w + 2 * q + h5;
        // --- tile A cell ---
        float siA = fsigmoid(accA[4 * q + 0]);
        float sfA = fsigmoid(accA[4 * q + 1]);
        float soA = fsigmoid(accA[4 * q + 3]);
        float cnA = sfA * cA[mm][q] + siA * ftanh(accA[4 * q + 2]);
        cA[mm][q] = cnA;
        float hlA = soA * ftanh(cnA);
        // --- tile B cell ---
        float siB = fsigmoid(accB[4 * q + 0]);
        float sfB = fsigmoid(accB[4 * q + 1]);
        float soB = fsigmoid(accB[4 * q + 3]);
        float cnB = sfB * cB[mm][q] + siB * ftanh(accB[4 * q + 2]);
        cB[mm][q] = cnB;
        float hlB = soB * ftanh(cnB);
        // --- shared threefry: pair (idx, idx + 2^22) = particles (pA, pA+128) ---
        uint32_t x0 = ((uint32_t)pA << 15) | bsh | (uint32_t)kq;
        uint32_t x1 = x0 + (1u << 22);
        threefry2x32(fk0, fk1, x0, x1);
        float eA = normal_from_bits(x0);
        float eB = normal_from_bits(x1);
        float hrA = fmaf(eA, std_r[q], hlA);
        float hrB = fmaf(eB, std_r[q], hlB);
        hrA_st[mm][q] = hrA;
        hrB_st[mm][q] = hrB;
        hs[q] += hrA + hrB;
        plA = fmaf(hrA, wf_r[q], plA); lpA = fmaf(hrA, wp_r[q], lpA);
        plB = fmaf(hrB, wf_r[q], plB); lpB = fmaf(hrB, wp_r[q], lpB);
      }
      plA += __shfl_xor(plA, 32, 64); lpA += __shfl_xor(lpA, 32, 64);
      plB += __shfl_xor(plB, 32, 64); lpB += __shfl_xor(lpB, 32, 64);
      if (lane < 32) {
        pp_s[w * NP + pA] = make_float2(plA, lpA);
        pp_s[w * NP + pB] = make_float2(plB, lpB);
      }
    }

    // hsum: reduce over 32-lane groups; k = 8w + 2q + h5 (both halves distinct)
    #pragma unroll
    for (int q = 0; q < 4; ++q) {
      float s = hs[q];
      s += __shfl_xor(s, 1, 64); s += __shfl_xor(s, 2, 64); s += __shfl_xor(s, 4, 64);
      s += __shfl_xor(s, 8, 64); s += __shfl_xor(s, 16, 64);
      if (ln31 == q) hsum_s[8 * w + 2 * q + h5] = s;
    }
    __syncthreads();   // b3: all MFMA reads of hbf done; pp_s complete

    // ---- phase 2b: write new h (unsorted rows) as bf16 splits ----
    #pragma unroll
    for (int mm = 0; mm < 4; ++mm) {
      const int pA = mm * 32 + ln31;
      #pragma unroll
      for (int q = 0; q < 4; ++q) {
        const int kq = 8 * w + 2 * q + h5;
        {
          float x = hrA_st[mm][q];
          uint16_t uh = bf16_rne(x);      float fh = bf16_to_f(uh);
          uint16_t um = bf16_rne(x - fh); float fm = bf16_to_f(um);
          uint16_t ul = bf16_rne(x - fh - fm);
          hbf_hi [pA * HROW + kq] = (short)uh;
          hbf_mid[pA * HROW + kq] = (short)um;
          hbf_lo [pA * HROW + kq] = (short)ul;
        }
        {
          float x = hrB_st[mm][q];
          uint16_t uh = bf16_rne(x);      float fh = bf16_to_f(uh);
          uint16_t um = bf16_rne(x - fh); float fm = bf16_to_f(um);
          uint16_t ul = bf16_rne(x - fh - fm);
          hbf_hi [(pA + 128) * HROW + kq] = (short)uh;
          hbf_mid[(pA + 128) * HROW + kq] = (short)um;
          hbf_lo [(pA + 128) * HROW + kq] = (short)ul;
        }
      }
    }
    float lpv = 0.0f;
    if (tid < NP) {
      float pv = bf0;
      #pragma unroll
      for (int ww = 0; ww < 8; ++ww) {
        float2 v = pp_s[ww * NP + tid];
        pv += v.x; lpv += v.y;
      }
      projC[tid] = pv;
    }
    __syncthreads();   // b4: projC + unsorted hbf ready

    // ---- phase 3: split stable-rank over both halves (128 candidates each) ----
    {
      const float projv = projC[ph];
      int rk = 0;
      const float4* c4 = (const float4*)projC;
      #pragma unroll 8
      for (int q4 = 32 * hh; q4 < 32 * hh + 32; ++q4) {
        float4 v = c4[q4];
        int qb = q4 * 4;
        rk += (v.x < projv || (v.x == projv && qb + 0 < ph)) ? 1 : 0;
        rk += (v.y < projv || (v.y == projv && qb + 1 < ph)) ? 1 : 0;
        rk += (v.z < projv || (v.z == projv && qb + 2 < ph)) ? 1 : 0;
        rk += (v.w < projv || (v.w == projv && qb + 3 < ph)) ? 1 : 0;
      }
      rankP_s[hh * NP + ph] = rk;
    }
    __syncthreads();   // b5: rank partials ready
    const int rank = rankP_s[ph] + rankP_s[NP + ph];

    if (tid < NP) {
      float xp = bp0;
      #pragma unroll
      for (int i = 0; i < NIN1; ++i) xp = fmaf(xs_s[i], wpx[i], xp);
      wsum_s[rank] += __expf(lpv + xp);   // ranks form a permutation -> race-free
    }

    // ---- permute: each thread moves half a row (32 shorts per array) ----
    {
      uint64_t rh[8], rm[8], rl[8];
      const int off = 32 * hh;
      #pragma unroll
      for (int c = 0; c < 8; ++c) {
        rh[c] = *(const uint64_t*)&hbf_hi [ph * HROW + off + 4 * c];
        rm[c] = *(const uint64_t*)&hbf_mid[ph * HROW + off + 4 * c];
        rl[c] = *(const uint64_t*)&hbf_lo [ph * HROW + off + 4 * c];
      }
      __syncthreads();   // b6: permute reads done
      #pragma unroll
      for (int c = 0; c < 8; ++c) {
        *(uint64_t*)&hbf_hi [rank * HROW + off + 4 * c] = rh[c];
        *(uint64_t*)&hbf_mid[rank * HROW + off + 4 * c] = rm[c];
        *(uint64_t*)&hbf_lo [rank * HROW + off + 4 * c] = rl[c];
      }
    }
    // loop-top barrier (b1) separates permute-writes from next step's reads
  }

  __syncthreads();
  // ---- epilogue: y_pred[b] = mean_p(h_fin) @ Wf + bf ----
  if (tid < NH) {
    float contrib = (hsum_s[tid] * (1.0f / NP)) * Wf[tid];
    contrib += __shfl_xor(contrib, 32, 64);
    contrib += __shfl_xor(contrib, 16, 64);
    contrib += __shfl_xor(contrib, 8, 64);
    contrib += __shfl_xor(contrib, 4, 64);
    contrib += __shfl_xor(contrib, 2, 64);
    contrib += __shfl_xor(contrib, 1, 64);
    if (tid == 0) out[b] = contrib + bf0;
  }
  if (tid < NP) gw[(size_t)tid * NB + b] = wsum_s[tid];
}

// weights[i] = (1/256) * sum_{j<256} gw[(i>>1)*512 + (i&1)*256 + j]
__global__ __launch_bounds__(64, 1)
void pf_weights(const float* __restrict__ gw, float* __restrict__ out) {
  int i = blockIdx.x;
  int lane = threadIdx.x;
  const float* src = gw + ((size_t)(i >> 1)) * NB + (size_t)(i & 1) * NP;
  float4 v = ((const float4*)src)[lane];
  float s = (v.x + v.y) + (v.z + v.w);
  s += __shfl_xor(s, 32, 64);
  s += __shfl_xor(s, 16, 64);
  s += __shfl_xor(s, 8, 64);
  s += __shfl_xor(s, 4, 64);
  s += __shfl_xor(s, 2, 64);
  s += __shfl_xor(s, 1, 64);
  if (lane == 0) out[NB + i] = s * (1.0f / NP);
}

extern "C" void kernel_launch(void* const* d_in, const int* in_sizes, int n_in,
                              void* d_out, int out_size, void* d_ws, size_t ws_size,
                              hipStream_t stream) {
  (void)in_sizes; (void)n_in; (void)out_size; (void)ws_size;
  const float* input_data = (const float*)d_in[0];
  const float* y_prev     = (const float*)d_in[1];
  const float* Wv         = (const float*)d_in[2];
  const float* bv         = (const float*)d_in[3];
  const float* W_ih       = (const float*)d_in[4];
  const float* W_hh       = (const float*)d_in[5];
  const float* b_ih       = (const float*)d_in[6];
  const float* b_hh       = (const float*)d_in[7];
  const float* Wp         = (const float*)d_in[8];
  const float* bp         = (const float*)d_in[9];
  const float* Wf         = (const float*)d_in[10];
  const float* bf         = (const float*)d_in[11];
  float* out = (float*)d_out;
  float* gw  = (float*)d_ws;                           // [P][B] f32 = 512 KB

  FKeys fk;
  for (int t = 0; t < NT; ++t) {
    uint32_t x0 = 0u, x1 = (uint32_t)t;
    threefry2x32(0u, 1234u, x0, x1);
    fk.a[t] = x0; fk.b[t] = x1;
  }

  pf_main<<<dim3(NB), dim3(NTHR), 0, stream>>>(
      input_data, y_prev, Wv, bv, W_ih, W_hh, b_ih, b_hh, Wp, bp, Wf, bf,
      out, gw, fk);
  pf_weights<<<dim3(NB), dim3(64), 0, stream>>>(gw, out);
}